// Round 2
// baseline (694.813 us; speedup 1.0000x reference)
//
#include <hip/hip_runtime.h>
#include <hip/hip_bf16.h>
#include <cstdint>
#include <cstddef>

#define LEAKY(x) ((x) > 0.f ? (x) : 0.2f * (x))

// ---------------------------------------------------------------- CSR build
__global__ void hist_dst(const int* __restrict__ ei, int E, int* __restrict__ deg) {
    int e = blockIdx.x * 256 + threadIdx.x;
    if (e < E) atomicAdd(&deg[ei[E + e]], 1);
}

// phase1: per-block (2048 elems) reduction -> blockSums
__global__ void scan_phase1(const int* __restrict__ deg, int n, int* __restrict__ bsum) {
    __shared__ int red[256];
    int t = threadIdx.x;
    int base = blockIdx.x * 2048;
    int s = 0;
#pragma unroll
    for (int i = 0; i < 8; ++i) {
        int idx = base + t * 8 + i;
        s += (idx < n) ? deg[idx] : 0;
    }
    red[t] = s;
    __syncthreads();
    for (int o = 128; o > 0; o >>= 1) {
        if (t < o) red[t] += red[t + o];
        __syncthreads();
    }
    if (t == 0) bsum[blockIdx.x] = red[0];
}

// phase2: exclusive scan of block sums (single thread; nb is small), write total
__global__ void scan_phase2(int* __restrict__ bsum, int nb, int* __restrict__ offsets, int n) {
    if (threadIdx.x == 0 && blockIdx.x == 0) {
        int run = 0;
        for (int i = 0; i < nb; ++i) {
            int v = bsum[i];
            bsum[i] = run;
            run += v;
        }
        offsets[n] = run;
    }
}

// phase3: block-local exclusive scan + block offset
__global__ void scan_phase3(const int* __restrict__ deg, int n, const int* __restrict__ bsum,
                            int* __restrict__ out) {
    __shared__ int sh[256];
    int t = threadIdx.x;
    int base = blockIdx.x * 2048;
    int loc[8];
    int s = 0;
#pragma unroll
    for (int i = 0; i < 8; ++i) {
        int idx = base + t * 8 + i;
        loc[i] = (idx < n) ? deg[idx] : 0;
        s += loc[i];
    }
    sh[t] = s;
    __syncthreads();
    for (int o = 1; o < 256; o <<= 1) {
        int add = (t >= o) ? sh[t - o] : 0;
        __syncthreads();
        sh[t] += add;
        __syncthreads();
    }
    int excl = sh[t] - s + bsum[blockIdx.x];
#pragma unroll
    for (int i = 0; i < 8; ++i) {
        int idx = base + t * 8 + i;
        if (idx < n) out[idx] = excl;
        excl += loc[i];
    }
}

__global__ void scatter_csr(const int* __restrict__ ei, int E, int* __restrict__ cursor,
                            int* __restrict__ csr) {
    int e = blockIdx.x * 256 + threadIdx.x;
    if (e < E) {
        int d = ei[E + e];
        int s = ei[e];
        int pos = atomicAdd(&cursor[d], 1);
        csr[pos] = s;
    }
}

// ---------------------------------------------------------------- GEMM (K=128 fixed)
// C[M,Nout] = A[M,128] @ B[128,Nout]; BM=64, BN=64, BK=16; 16x16 threads, 4x4 micro-tile
__global__ void gemm_k128(const float* __restrict__ A, const float* __restrict__ B,
                          float* __restrict__ C, int M, int Nout) {
    __shared__ float As[16][68];  // [kk][row]
    __shared__ float Bs[16][68];  // [kk][col]
    const int tid = threadIdx.y * 16 + threadIdx.x;
    const int row0 = blockIdx.x * 64;
    const int col0 = blockIdx.y * 64;
    float acc[4][4] = {};
    for (int k0 = 0; k0 < 128; k0 += 16) {
        {
            int idx = tid * 4;
            int r = idx >> 4;        // 0..63
            int c = idx & 15;        // 0,4,8,12
            float4 v = make_float4(0.f, 0.f, 0.f, 0.f);
            if (row0 + r < M)
                v = *(const float4*)(A + (size_t)(row0 + r) * 128 + k0 + c);
            As[c][r] = v.x; As[c + 1][r] = v.y; As[c + 2][r] = v.z; As[c + 3][r] = v.w;
        }
        {
            int idx = tid * 4;
            int r = idx >> 6;        // 0..15
            int c = idx & 63;        // multiple of 4
            float4 v = *(const float4*)(B + (size_t)(k0 + r) * Nout + col0 + c);
            Bs[r][c] = v.x; Bs[r][c + 1] = v.y; Bs[r][c + 2] = v.z; Bs[r][c + 3] = v.w;
        }
        __syncthreads();
#pragma unroll
        for (int kk = 0; kk < 16; ++kk) {
            float a[4], b[4];
#pragma unroll
            for (int i = 0; i < 4; ++i) a[i] = As[kk][threadIdx.y * 4 + i];
#pragma unroll
            for (int j = 0; j < 4; ++j) b[j] = Bs[kk][threadIdx.x * 4 + j];
#pragma unroll
            for (int i = 0; i < 4; ++i)
#pragma unroll
                for (int j = 0; j < 4; ++j) acc[i][j] += a[i] * b[j];
        }
        __syncthreads();
    }
#pragma unroll
    for (int i = 0; i < 4; ++i) {
        int r = row0 + threadIdx.y * 4 + i;
        if (r < M) {
#pragma unroll
            for (int j = 0; j < 4; ++j)
                C[(size_t)r * Nout + col0 + threadIdx.x * 4 + j] = acc[i][j];
        }
    }
}

// ---------------------------------------------------------------- attention scores
// layer1: 2 heads x 64ch; one wave per node
__global__ void att_scores_h2(const float* __restrict__ h, const float* __restrict__ att_src,
                              const float* __restrict__ att_dst, float* __restrict__ asrc,
                              float* __restrict__ adst, int N) {
    int wid = (blockIdx.x * blockDim.x + threadIdx.x) >> 6;
    int lane = threadIdx.x & 63;
    if (wid >= N) return;
    const float* row = h + (size_t)wid * 128;
    float h0 = row[lane], h1 = row[64 + lane];
    float s0 = h0 * att_src[lane], s1 = h1 * att_src[64 + lane];
    float d0 = h0 * att_dst[lane], d1 = h1 * att_dst[64 + lane];
    for (int m = 32; m > 0; m >>= 1) {
        s0 += __shfl_xor(s0, m);
        s1 += __shfl_xor(s1, m);
        d0 += __shfl_xor(d0, m);
        d1 += __shfl_xor(d1, m);
    }
    if (lane == 0) {
        asrc[wid * 2] = s0; asrc[wid * 2 + 1] = s1;
        adst[wid * 2] = d0; adst[wid * 2 + 1] = d1;
    }
}

// layer2: 1 head x 64ch
__global__ void att_scores_h1(const float* __restrict__ h, const float* __restrict__ att_src,
                              const float* __restrict__ att_dst, float* __restrict__ asrc,
                              float* __restrict__ adst, int N) {
    int wid = (blockIdx.x * blockDim.x + threadIdx.x) >> 6;
    int lane = threadIdx.x & 63;
    if (wid >= N) return;
    float hv = h[(size_t)wid * 64 + lane];
    float s = hv * att_src[lane];
    float d = hv * att_dst[lane];
    for (int m = 32; m > 0; m >>= 1) {
        s += __shfl_xor(s, m);
        d += __shfl_xor(d, m);
    }
    if (lane == 0) {
        asrc[wid] = s;
        adst[wid] = d;
    }
}

// ---------------------------------------------------------------- fused softmax+aggregate
// layer1: 2 heads, channels = lane (h0) and 64+lane (h1). out = relu(agg + bias)
__global__ void agg_layer1(const float* __restrict__ h1, const float* __restrict__ asrc,
                           const float* __restrict__ adst, const int* __restrict__ offs,
                           const int* __restrict__ csr, const float* __restrict__ bias,
                           float* __restrict__ out, int N) {
    int wid = (blockIdx.x * blockDim.x + threadIdx.x) >> 6;
    int lane = threadIdx.x & 63;
    if (wid >= N) return;
    int off = offs[wid], end = offs[wid + 1];
    float ad0 = adst[2 * wid], ad1 = adst[2 * wid + 1];
    float self0 = LEAKY(asrc[2 * wid] + ad0);
    float self1 = LEAKY(asrc[2 * wid + 1] + ad1);
    float m0 = self0, m1 = self1;
    for (int e = off + lane; e < end; e += 64) {
        int s = csr[e];
        m0 = fmaxf(m0, LEAKY(asrc[2 * s] + ad0));
        m1 = fmaxf(m1, LEAKY(asrc[2 * s + 1] + ad1));
    }
    for (int o = 32; o > 0; o >>= 1) {
        m0 = fmaxf(m0, __shfl_xor(m0, o));
        m1 = fmaxf(m1, __shfl_xor(m1, o));
    }
    float w0 = __expf(self0 - m0);
    float w1 = __expf(self1 - m1);
    float sum0 = w0, sum1 = w1;
    float acc0 = w0 * h1[(size_t)wid * 128 + lane];
    float acc1 = w1 * h1[(size_t)wid * 128 + 64 + lane];
    for (int e = off; e < end; ++e) {
        int s = csr[e];
        float a0 = LEAKY(asrc[2 * s] + ad0);
        float a1 = LEAKY(asrc[2 * s + 1] + ad1);
        float e0 = __expf(a0 - m0);
        float e1 = __expf(a1 - m1);
        sum0 += e0;
        sum1 += e1;
        acc0 += e0 * h1[(size_t)s * 128 + lane];
        acc1 += e1 * h1[(size_t)s * 128 + 64 + lane];
    }
    float o0 = acc0 / (sum0 + 1e-16f) + bias[lane];
    float o1 = acc1 / (sum1 + 1e-16f) + bias[64 + lane];
    out[(size_t)wid * 128 + lane] = fmaxf(o0, 0.f);
    out[(size_t)wid * 128 + 64 + lane] = fmaxf(o1, 0.f);
}

// layer2: 1 head, 64 channels, no relu
__global__ void agg_layer2(const float* __restrict__ h2, const float* __restrict__ asrc,
                           const float* __restrict__ adst, const int* __restrict__ offs,
                           const int* __restrict__ csr, const float* __restrict__ bias,
                           float* __restrict__ out, int N) {
    int wid = (blockIdx.x * blockDim.x + threadIdx.x) >> 6;
    int lane = threadIdx.x & 63;
    if (wid >= N) return;
    int off = offs[wid], end = offs[wid + 1];
    float ad = adst[wid];
    float self = LEAKY(asrc[wid] + ad);
    float m = self;
    for (int e = off + lane; e < end; e += 64) {
        int s = csr[e];
        m = fmaxf(m, LEAKY(asrc[s] + ad));
    }
    for (int o = 32; o > 0; o >>= 1) m = fmaxf(m, __shfl_xor(m, o));
    float w = __expf(self - m);
    float sum = w;
    float acc = w * h2[(size_t)wid * 64 + lane];
    for (int e = off; e < end; ++e) {
        int s = csr[e];
        float ee = __expf(LEAKY(asrc[s] + ad) - m);
        sum += ee;
        acc += ee * h2[(size_t)s * 64 + lane];
    }
    out[(size_t)wid * 64 + lane] = acc / (sum + 1e-16f) + bias[lane];
}

// ---------------------------------------------------------------- host
extern "C" void kernel_launch(void* const* d_in, const int* in_sizes, int n_in,
                              void* d_out, int out_size, void* d_ws, size_t ws_size,
                              hipStream_t stream) {
    const float* x        = (const float*)d_in[0];
    const int* ei         = (const int*)d_in[1];   // int64 in reference -> int32 here
    const float* W1       = (const float*)d_in[2];
    const float* att_src1 = (const float*)d_in[3];
    const float* att_dst1 = (const float*)d_in[4];
    const float* bias1    = (const float*)d_in[5];
    const float* W2       = (const float*)d_in[6];
    const float* att_src2 = (const float*)d_in[7];
    const float* att_dst2 = (const float*)d_in[8];
    const float* bias2    = (const float*)d_in[9];

    const int N = in_sizes[0] / 128;  // 100000
    const int E = in_sizes[1] / 2;    // 1600000

    // workspace carve-up (256B aligned)
    char* base = (char*)d_ws;
    size_t off = 0;
    auto alloc = [&](size_t bytes) {
        char* p = base + off;
        off = (off + bytes + 255) & ~(size_t)255;
        return p;
    };
    int*   deg     = (int*)alloc((size_t)N * 4);
    int*   offsets = (int*)alloc((size_t)(N + 1) * 4);
    int*   cursor  = (int*)alloc((size_t)N * 4);
    int*   bsum    = (int*)alloc(4096);
    int*   csr     = (int*)alloc((size_t)E * 4);
    float* h1      = (float*)alloc((size_t)N * 128 * 4);  // reused as h2 later
    float* out1    = (float*)alloc((size_t)N * 128 * 4);
    float* asrc1   = (float*)alloc((size_t)N * 2 * 4);
    float* adst1   = (float*)alloc((size_t)N * 2 * 4);
    float* asrc2   = (float*)alloc((size_t)N * 4);
    float* adst2   = (float*)alloc((size_t)N * 4);
    float* h2      = h1;  // layer1 features dead after agg_layer1

    const int nb = (N + 2047) / 2048;

    // --- CSR build (shared by both layers) ---
    hipMemsetAsync(deg, 0, (size_t)N * 4, stream);
    hist_dst<<<(E + 255) / 256, 256, 0, stream>>>(ei, E, deg);
    scan_phase1<<<nb, 256, 0, stream>>>(deg, N, bsum);
    scan_phase2<<<1, 64, 0, stream>>>(bsum, nb, offsets, N);
    scan_phase3<<<nb, 256, 0, stream>>>(deg, N, bsum, offsets);
    hipMemcpyAsync(cursor, offsets, (size_t)N * 4, hipMemcpyDeviceToDevice, stream);
    scatter_csr<<<(E + 255) / 256, 256, 0, stream>>>(ei, E, cursor, csr);

    const int mblocks = (N + 63) / 64;
    const int nwave_blocks = (N + 3) / 4;  // 4 waves per 256-thread block

    // --- layer 1 ---
    gemm_k128<<<dim3(mblocks, 2), dim3(16, 16), 0, stream>>>(x, W1, h1, N, 128);
    att_scores_h2<<<nwave_blocks, 256, 0, stream>>>(h1, att_src1, att_dst1, asrc1, adst1, N);
    agg_layer1<<<nwave_blocks, 256, 0, stream>>>(h1, asrc1, adst1, offsets, csr, bias1, out1, N);

    // --- layer 2 ---
    gemm_k128<<<dim3(mblocks, 1), dim3(16, 16), 0, stream>>>(out1, W2, h2, N, 64);
    att_scores_h1<<<nwave_blocks, 256, 0, stream>>>(h2, att_src2, att_dst2, asrc2, adst2, N);
    agg_layer2<<<nwave_blocks, 256, 0, stream>>>(h2, asrc2, adst2, offsets, csr, bias2,
                                                 (float*)d_out, N);
}

// Round 3
// 598.615 us; speedup vs baseline: 1.1607x; 1.1607x over previous
//
#include <hip/hip_runtime.h>
#include <hip/hip_bf16.h>
#include <cstdint>
#include <cstddef>

#define LEAKY(x) ((x) > 0.f ? (x) : 0.2f * (x))

// ---------------------------------------------------------------- CSR build
__global__ void hist_dst(const int* __restrict__ ei, int E, int* __restrict__ deg) {
    int e = blockIdx.x * 256 + threadIdx.x;
    if (e < E) atomicAdd(&deg[ei[E + e]], 1);
}

__global__ void scan_phase1(const int* __restrict__ deg, int n, int* __restrict__ bsum) {
    __shared__ int red[256];
    int t = threadIdx.x;
    int base = blockIdx.x * 2048;
    int s = 0;
#pragma unroll
    for (int i = 0; i < 8; ++i) {
        int idx = base + t * 8 + i;
        s += (idx < n) ? deg[idx] : 0;
    }
    red[t] = s;
    __syncthreads();
    for (int o = 128; o > 0; o >>= 1) {
        if (t < o) red[t] += red[t + o];
        __syncthreads();
    }
    if (t == 0) bsum[blockIdx.x] = red[0];
}

__global__ void scan_phase2(int* __restrict__ bsum, int nb, int* __restrict__ offsets, int n) {
    if (threadIdx.x == 0 && blockIdx.x == 0) {
        int run = 0;
        for (int i = 0; i < nb; ++i) {
            int v = bsum[i];
            bsum[i] = run;
            run += v;
        }
        offsets[n] = run;
    }
}

__global__ void scan_phase3(const int* __restrict__ deg, int n, const int* __restrict__ bsum,
                            int* __restrict__ out) {
    __shared__ int sh[256];
    int t = threadIdx.x;
    int base = blockIdx.x * 2048;
    int loc[8];
    int s = 0;
#pragma unroll
    for (int i = 0; i < 8; ++i) {
        int idx = base + t * 8 + i;
        loc[i] = (idx < n) ? deg[idx] : 0;
        s += loc[i];
    }
    sh[t] = s;
    __syncthreads();
    for (int o = 1; o < 256; o <<= 1) {
        int add = (t >= o) ? sh[t - o] : 0;
        __syncthreads();
        sh[t] += add;
        __syncthreads();
    }
    int excl = sh[t] - s + bsum[blockIdx.x];
#pragma unroll
    for (int i = 0; i < 8; ++i) {
        int idx = base + t * 8 + i;
        if (idx < n) out[idx] = excl;
        excl += loc[i];
    }
}

__global__ void scatter_csr(const int* __restrict__ ei, int E, int* __restrict__ cursor,
                            int* __restrict__ csr) {
    int e = blockIdx.x * 256 + threadIdx.x;
    if (e < E) {
        int d = ei[E + e];
        int s = ei[e];
        int pos = atomicAdd(&cursor[d], 1);
        csr[pos] = s;
    }
}

// ---------------------------------------------------------------- GEMM (K=128 fixed)
__global__ void gemm_k128(const float* __restrict__ A, const float* __restrict__ B,
                          float* __restrict__ C, int M, int Nout) {
    __shared__ float As[16][68];
    __shared__ float Bs[16][68];
    const int tid = threadIdx.y * 16 + threadIdx.x;
    const int row0 = blockIdx.x * 64;
    const int col0 = blockIdx.y * 64;
    float acc[4][4] = {};
    for (int k0 = 0; k0 < 128; k0 += 16) {
        {
            int idx = tid * 4;
            int r = idx >> 4;
            int c = idx & 15;
            float4 v = make_float4(0.f, 0.f, 0.f, 0.f);
            if (row0 + r < M)
                v = *(const float4*)(A + (size_t)(row0 + r) * 128 + k0 + c);
            As[c][r] = v.x; As[c + 1][r] = v.y; As[c + 2][r] = v.z; As[c + 3][r] = v.w;
        }
        {
            int idx = tid * 4;
            int r = idx >> 6;
            int c = idx & 63;
            float4 v = *(const float4*)(B + (size_t)(k0 + r) * Nout + col0 + c);
            Bs[r][c] = v.x; Bs[r][c + 1] = v.y; Bs[r][c + 2] = v.z; Bs[r][c + 3] = v.w;
        }
        __syncthreads();
#pragma unroll
        for (int kk = 0; kk < 16; ++kk) {
            float a[4], b[4];
#pragma unroll
            for (int i = 0; i < 4; ++i) a[i] = As[kk][threadIdx.y * 4 + i];
#pragma unroll
            for (int j = 0; j < 4; ++j) b[j] = Bs[kk][threadIdx.x * 4 + j];
#pragma unroll
            for (int i = 0; i < 4; ++i)
#pragma unroll
                for (int j = 0; j < 4; ++j) acc[i][j] += a[i] * b[j];
        }
        __syncthreads();
    }
#pragma unroll
    for (int i = 0; i < 4; ++i) {
        int r = row0 + threadIdx.y * 4 + i;
        if (r < M) {
#pragma unroll
            for (int j = 0; j < 4; ++j)
                C[(size_t)r * Nout + col0 + threadIdx.x * 4 + j] = acc[i][j];
        }
    }
}

// ---------------------------------------------------------------- attention scores
__global__ void att_scores_h2(const float* __restrict__ h, const float* __restrict__ att_src,
                              const float* __restrict__ att_dst, float* __restrict__ asrc,
                              float* __restrict__ adst, int N) {
    int wid = (blockIdx.x * blockDim.x + threadIdx.x) >> 6;
    int lane = threadIdx.x & 63;
    if (wid >= N) return;
    const float* row = h + (size_t)wid * 128;
    float h0 = row[lane], h1 = row[64 + lane];
    float s0 = h0 * att_src[lane], s1 = h1 * att_src[64 + lane];
    float d0 = h0 * att_dst[lane], d1 = h1 * att_dst[64 + lane];
    for (int m = 32; m > 0; m >>= 1) {
        s0 += __shfl_xor(s0, m);
        s1 += __shfl_xor(s1, m);
        d0 += __shfl_xor(d0, m);
        d1 += __shfl_xor(d1, m);
    }
    if (lane == 0) {
        asrc[wid * 2] = s0; asrc[wid * 2 + 1] = s1;
        adst[wid * 2] = d0; adst[wid * 2 + 1] = d1;
    }
}

__global__ void att_scores_h1(const float* __restrict__ h, const float* __restrict__ att_src,
                              const float* __restrict__ att_dst, float* __restrict__ asrc,
                              float* __restrict__ adst, int N) {
    int wid = (blockIdx.x * blockDim.x + threadIdx.x) >> 6;
    int lane = threadIdx.x & 63;
    if (wid >= N) return;
    float hv = h[(size_t)wid * 64 + lane];
    float s = hv * att_src[lane];
    float d = hv * att_dst[lane];
    for (int m = 32; m > 0; m >>= 1) {
        s += __shfl_xor(s, m);
        d += __shfl_xor(d, m);
    }
    if (lane == 0) {
        asrc[wid] = s;
        adst[wid] = d;
    }
}

// ---------------------------------------------------------------- fused softmax+aggregate
// layer1: one wave per (node, head); lane = channel within head. MLP via 4x unroll.
__global__ void agg_layer1(const float* __restrict__ h1, const float* __restrict__ asrc,
                           const float* __restrict__ adst, const int* __restrict__ offs,
                           const int* __restrict__ csr, const float* __restrict__ bias,
                           float* __restrict__ out, int N) {
    int wid = (blockIdx.x * blockDim.x + threadIdx.x) >> 6;
    int lane = threadIdx.x & 63;
    if (wid >= 2 * N) return;
    int node = wid >> 1, head = wid & 1;
    int off = offs[node], end = offs[node + 1];
    float ad = adst[2 * node + head];
    float self = LEAKY(asrc[2 * node + head] + ad);
    float m = self;
    for (int e = off + lane; e < end; e += 64) {
        m = fmaxf(m, LEAKY(asrc[2 * csr[e] + head] + ad));
    }
    for (int o = 32; o > 0; o >>= 1) m = fmaxf(m, __shfl_xor(m, o));
    const float* hh = h1 + head * 64;
    float w = __expf(self - m);
    float sum = w;
    float acc = w * hh[(size_t)node * 128 + lane];
    int e = off;
    for (; e + 4 <= end; e += 4) {
        int s0 = csr[e], s1 = csr[e + 1], s2 = csr[e + 2], s3 = csr[e + 3];
        float v0 = hh[(size_t)s0 * 128 + lane];
        float v1 = hh[(size_t)s1 * 128 + lane];
        float v2 = hh[(size_t)s2 * 128 + lane];
        float v3 = hh[(size_t)s3 * 128 + lane];
        float e0 = __expf(LEAKY(asrc[2 * s0 + head] + ad) - m);
        float e1 = __expf(LEAKY(asrc[2 * s1 + head] + ad) - m);
        float e2 = __expf(LEAKY(asrc[2 * s2 + head] + ad) - m);
        float e3 = __expf(LEAKY(asrc[2 * s3 + head] + ad) - m);
        sum += (e0 + e1) + (e2 + e3);
        acc += e0 * v0;
        acc += e1 * v1;
        acc += e2 * v2;
        acc += e3 * v3;
    }
    for (; e < end; ++e) {
        int s = csr[e];
        float v = hh[(size_t)s * 128 + lane];
        float ee = __expf(LEAKY(asrc[2 * s + head] + ad) - m);
        sum += ee;
        acc += ee * v;
    }
    float o0 = acc / (sum + 1e-16f) + bias[head * 64 + lane];
    out[(size_t)node * 128 + head * 64 + lane] = fmaxf(o0, 0.f);
}

// layer2: one wave per node, 1 head, 64 channels, no relu. 4x unroll.
__global__ void agg_layer2(const float* __restrict__ h2, const float* __restrict__ asrc,
                           const float* __restrict__ adst, const int* __restrict__ offs,
                           const int* __restrict__ csr, const float* __restrict__ bias,
                           float* __restrict__ out, int N) {
    int wid = (blockIdx.x * blockDim.x + threadIdx.x) >> 6;
    int lane = threadIdx.x & 63;
    if (wid >= N) return;
    int off = offs[wid], end = offs[wid + 1];
    float ad = adst[wid];
    float self = LEAKY(asrc[wid] + ad);
    float m = self;
    for (int e = off + lane; e < end; e += 64) {
        m = fmaxf(m, LEAKY(asrc[csr[e]] + ad));
    }
    for (int o = 32; o > 0; o >>= 1) m = fmaxf(m, __shfl_xor(m, o));
    float w = __expf(self - m);
    float sum = w;
    float acc = w * h2[(size_t)wid * 64 + lane];
    int e = off;
    for (; e + 4 <= end; e += 4) {
        int s0 = csr[e], s1 = csr[e + 1], s2 = csr[e + 2], s3 = csr[e + 3];
        float v0 = h2[(size_t)s0 * 64 + lane];
        float v1 = h2[(size_t)s1 * 64 + lane];
        float v2 = h2[(size_t)s2 * 64 + lane];
        float v3 = h2[(size_t)s3 * 64 + lane];
        float e0 = __expf(LEAKY(asrc[s0] + ad) - m);
        float e1 = __expf(LEAKY(asrc[s1] + ad) - m);
        float e2 = __expf(LEAKY(asrc[s2] + ad) - m);
        float e3 = __expf(LEAKY(asrc[s3] + ad) - m);
        sum += (e0 + e1) + (e2 + e3);
        acc += e0 * v0;
        acc += e1 * v1;
        acc += e2 * v2;
        acc += e3 * v3;
    }
    for (; e < end; ++e) {
        int s = csr[e];
        float v = h2[(size_t)s * 64 + lane];
        float ee = __expf(LEAKY(asrc[s] + ad) - m);
        sum += ee;
        acc += ee * v;
    }
    out[(size_t)wid * 64 + lane] = acc / (sum + 1e-16f) + bias[lane];
}

// ---------------------------------------------------------------- host
extern "C" void kernel_launch(void* const* d_in, const int* in_sizes, int n_in,
                              void* d_out, int out_size, void* d_ws, size_t ws_size,
                              hipStream_t stream) {
    const float* x        = (const float*)d_in[0];
    const int* ei         = (const int*)d_in[1];
    const float* W1       = (const float*)d_in[2];
    const float* att_src1 = (const float*)d_in[3];
    const float* att_dst1 = (const float*)d_in[4];
    const float* bias1    = (const float*)d_in[5];
    const float* W2       = (const float*)d_in[6];
    const float* att_src2 = (const float*)d_in[7];
    const float* att_dst2 = (const float*)d_in[8];
    const float* bias2    = (const float*)d_in[9];

    const int N = in_sizes[0] / 128;  // 100000
    const int E = in_sizes[1] / 2;    // 1600000

    char* base = (char*)d_ws;
    size_t off = 0;
    auto alloc = [&](size_t bytes) {
        char* p = base + off;
        off = (off + bytes + 255) & ~(size_t)255;
        return p;
    };
    int*   deg     = (int*)alloc((size_t)N * 4);
    int*   offsets = (int*)alloc((size_t)(N + 1) * 4);
    int*   cursor  = (int*)alloc((size_t)N * 4);
    int*   bsum    = (int*)alloc(4096);
    int*   csr     = (int*)alloc((size_t)E * 4);
    float* h1      = (float*)alloc((size_t)N * 128 * 4);
    float* out1    = (float*)alloc((size_t)N * 128 * 4);
    float* asrc1   = (float*)alloc((size_t)N * 2 * 4);
    float* adst1   = (float*)alloc((size_t)N * 2 * 4);
    float* asrc2   = (float*)alloc((size_t)N * 4);
    float* adst2   = (float*)alloc((size_t)N * 4);
    float* h2      = h1;

    const int nb = (N + 2047) / 2048;

    hipMemsetAsync(deg, 0, (size_t)N * 4, stream);
    hist_dst<<<(E + 255) / 256, 256, 0, stream>>>(ei, E, deg);
    scan_phase1<<<nb, 256, 0, stream>>>(deg, N, bsum);
    scan_phase2<<<1, 64, 0, stream>>>(bsum, nb, offsets, N);
    scan_phase3<<<nb, 256, 0, stream>>>(deg, N, bsum, offsets);
    hipMemcpyAsync(cursor, offsets, (size_t)N * 4, hipMemcpyDeviceToDevice, stream);
    scatter_csr<<<(E + 255) / 256, 256, 0, stream>>>(ei, E, cursor, csr);

    const int mblocks = (N + 63) / 64;
    const int nwave_blocks = (N + 3) / 4;       // 4 waves / block
    const int nwave_blocks2 = (2 * N + 3) / 4;  // (node,head) waves for layer1

    // --- layer 1 ---
    gemm_k128<<<dim3(mblocks, 2), dim3(16, 16), 0, stream>>>(x, W1, h1, N, 128);
    att_scores_h2<<<nwave_blocks, 256, 0, stream>>>(h1, att_src1, att_dst1, asrc1, adst1, N);
    agg_layer1<<<nwave_blocks2, 256, 0, stream>>>(h1, asrc1, adst1, offsets, csr, bias1, out1, N);

    // --- layer 2 ---
    gemm_k128<<<dim3(mblocks, 1), dim3(16, 16), 0, stream>>>(out1, W2, h2, N, 64);
    att_scores_h1<<<nwave_blocks, 256, 0, stream>>>(h2, att_src2, att_dst2, asrc2, adst2, N);
    agg_layer2<<<nwave_blocks, 256, 0, stream>>>(h2, asrc2, adst2, offsets, csr, bias2,
                                                 (float*)d_out, N);
}

// Round 4
// 544.137 us; speedup vs baseline: 1.2769x; 1.1001x over previous
//
#include <hip/hip_runtime.h>
#include <hip/hip_bf16.h>
#include <cstdint>
#include <cstddef>

#define LEAKY(x) ((x) > 0.f ? (x) : 0.2f * (x))

__device__ __forceinline__ float readlane_f(float v, int l) {
    return __int_as_float(__builtin_amdgcn_readlane(__float_as_int(v), l));
}

// ---------------------------------------------------------------- CSR build
__global__ void hist_dst(const int* __restrict__ ei, int E, int* __restrict__ deg) {
    int e = blockIdx.x * 256 + threadIdx.x;
    if (e < E) atomicAdd(&deg[ei[E + e]], 1);
}

__global__ void scan_phase1(const int* __restrict__ deg, int n, int* __restrict__ bsum) {
    __shared__ int red[256];
    int t = threadIdx.x;
    int base = blockIdx.x * 2048;
    int s = 0;
#pragma unroll
    for (int i = 0; i < 8; ++i) {
        int idx = base + t * 8 + i;
        s += (idx < n) ? deg[idx] : 0;
    }
    red[t] = s;
    __syncthreads();
    for (int o = 128; o > 0; o >>= 1) {
        if (t < o) red[t] += red[t + o];
        __syncthreads();
    }
    if (t == 0) bsum[blockIdx.x] = red[0];
}

__global__ void scan_phase2(int* __restrict__ bsum, int nb, int* __restrict__ offsets, int n) {
    if (threadIdx.x == 0 && blockIdx.x == 0) {
        int run = 0;
        for (int i = 0; i < nb; ++i) {
            int v = bsum[i];
            bsum[i] = run;
            run += v;
        }
        offsets[n] = run;
    }
}

__global__ void scan_phase3(const int* __restrict__ deg, int n, const int* __restrict__ bsum,
                            int* __restrict__ out) {
    __shared__ int sh[256];
    int t = threadIdx.x;
    int base = blockIdx.x * 2048;
    int loc[8];
    int s = 0;
#pragma unroll
    for (int i = 0; i < 8; ++i) {
        int idx = base + t * 8 + i;
        loc[i] = (idx < n) ? deg[idx] : 0;
        s += loc[i];
    }
    sh[t] = s;
    __syncthreads();
    for (int o = 1; o < 256; o <<= 1) {
        int add = (t >= o) ? sh[t - o] : 0;
        __syncthreads();
        sh[t] += add;
        __syncthreads();
    }
    int excl = sh[t] - s + bsum[blockIdx.x];
#pragma unroll
    for (int i = 0; i < 8; ++i) {
        int idx = base + t * 8 + i;
        if (idx < n) out[idx] = excl;
        excl += loc[i];
    }
}

__global__ void scatter_csr(const int* __restrict__ ei, int E, int* __restrict__ cursor,
                            int* __restrict__ csr) {
    int e = blockIdx.x * 256 + threadIdx.x;
    if (e < E) {
        int d = ei[E + e];
        int s = ei[e];
        int pos = atomicAdd(&cursor[d], 1);
        csr[pos] = s;
    }
}

// ---------------------------------------------------------------- GEMM (K=128 fixed)
__global__ void gemm_k128(const float* __restrict__ A, const float* __restrict__ B,
                          float* __restrict__ C, int M, int Nout) {
    __shared__ float As[16][68];
    __shared__ float Bs[16][68];
    const int tid = threadIdx.y * 16 + threadIdx.x;
    const int row0 = blockIdx.x * 64;
    const int col0 = blockIdx.y * 64;
    float acc[4][4] = {};
    for (int k0 = 0; k0 < 128; k0 += 16) {
        {
            int idx = tid * 4;
            int r = idx >> 4;
            int c = idx & 15;
            float4 v = make_float4(0.f, 0.f, 0.f, 0.f);
            if (row0 + r < M)
                v = *(const float4*)(A + (size_t)(row0 + r) * 128 + k0 + c);
            As[c][r] = v.x; As[c + 1][r] = v.y; As[c + 2][r] = v.z; As[c + 3][r] = v.w;
        }
        {
            int idx = tid * 4;
            int r = idx >> 6;
            int c = idx & 63;
            float4 v = *(const float4*)(B + (size_t)(k0 + r) * Nout + col0 + c);
            Bs[r][c] = v.x; Bs[r][c + 1] = v.y; Bs[r][c + 2] = v.z; Bs[r][c + 3] = v.w;
        }
        __syncthreads();
#pragma unroll
        for (int kk = 0; kk < 16; ++kk) {
            float a[4], b[4];
#pragma unroll
            for (int i = 0; i < 4; ++i) a[i] = As[kk][threadIdx.y * 4 + i];
#pragma unroll
            for (int j = 0; j < 4; ++j) b[j] = Bs[kk][threadIdx.x * 4 + j];
#pragma unroll
            for (int i = 0; i < 4; ++i)
#pragma unroll
                for (int j = 0; j < 4; ++j) acc[i][j] += a[i] * b[j];
        }
        __syncthreads();
    }
#pragma unroll
    for (int i = 0; i < 4; ++i) {
        int r = row0 + threadIdx.y * 4 + i;
        if (r < M) {
#pragma unroll
            for (int j = 0; j < 4; ++j)
                C[(size_t)r * Nout + col0 + threadIdx.x * 4 + j] = acc[i][j];
        }
    }
}

// ---------------------------------------------------------------- attention scores
__global__ void att_scores_h2(const float* __restrict__ h, const float* __restrict__ att_src,
                              const float* __restrict__ att_dst, float* __restrict__ asrc,
                              float* __restrict__ adst, int N) {
    int wid = (blockIdx.x * blockDim.x + threadIdx.x) >> 6;
    int lane = threadIdx.x & 63;
    if (wid >= N) return;
    const float* row = h + (size_t)wid * 128;
    float h0 = row[lane], h1 = row[64 + lane];
    float s0 = h0 * att_src[lane], s1 = h1 * att_src[64 + lane];
    float d0 = h0 * att_dst[lane], d1 = h1 * att_dst[64 + lane];
    for (int m = 32; m > 0; m >>= 1) {
        s0 += __shfl_xor(s0, m);
        s1 += __shfl_xor(s1, m);
        d0 += __shfl_xor(d0, m);
        d1 += __shfl_xor(d1, m);
    }
    if (lane == 0) {
        asrc[wid * 2] = s0; asrc[wid * 2 + 1] = s1;
        adst[wid * 2] = d0; adst[wid * 2 + 1] = d1;
    }
}

__global__ void att_scores_h1(const float* __restrict__ h, const float* __restrict__ att_src,
                              const float* __restrict__ att_dst, float* __restrict__ asrc,
                              float* __restrict__ adst, int N) {
    int wid = (blockIdx.x * blockDim.x + threadIdx.x) >> 6;
    int lane = threadIdx.x & 63;
    if (wid >= N) return;
    float hv = h[(size_t)wid * 64 + lane];
    float s = hv * att_src[lane];
    float d = hv * att_dst[lane];
    for (int m = 32; m > 0; m >>= 1) {
        s += __shfl_xor(s, m);
        d += __shfl_xor(d, m);
    }
    if (lane == 0) {
        asrc[wid] = s;
        adst[wid] = d;
    }
}

// ---------------------------------------------------------------- fused softmax+aggregate
// One wave per (node, head). Lane-parallel score/exp; readlane-broadcast gather-FMA.
__global__ void agg_layer1(const float* __restrict__ h1, const float* __restrict__ asrc,
                           const float* __restrict__ adst, const int* __restrict__ offs,
                           const int* __restrict__ csr, const float* __restrict__ bias,
                           float* __restrict__ out, int N) {
    int wid = (blockIdx.x * blockDim.x + threadIdx.x) >> 6;
    int lane = threadIdx.x & 63;
    if (wid >= 2 * N) return;
    int node = wid >> 1, head = wid & 1;
    int off = offs[node], end = offs[node + 1];
    float ad = adst[2 * node + head];
    float self = LEAKY(asrc[2 * node + head] + ad);

    // ---- max phase; cache first-chunk scores in registers
    int e0 = off + lane;
    int s_reg = 0;
    float alpha_reg = -1e30f;
    if (e0 < end) {
        s_reg = csr[e0];
        alpha_reg = LEAKY(asrc[2 * s_reg + head] + ad);
    }
    float m = fmaxf(self, alpha_reg);
    for (int e = off + 64 + lane; e < end; e += 64) {
        m = fmaxf(m, LEAKY(asrc[2 * csr[e] + head] + ad));
    }
#pragma unroll
    for (int o = 32; o > 0; o >>= 1) m = fmaxf(m, __shfl_xor(m, o));

    const float* hh = h1 + head * 64;
    float wself = __expf(self - m);
    float sum = wself;
    float acc = wself * hh[(size_t)node * 128 + lane];

    for (int chunk = off; chunk < end; chunk += 64) {
        float w;
        int s;
        if (chunk == off) {
            s = s_reg;
            w = (e0 < end) ? __expf(alpha_reg - m) : 0.f;
        } else {
            int e = chunk + lane;
            s = 0;
            w = 0.f;
            if (e < end) {
                s = csr[e];
                w = __expf(LEAKY(asrc[2 * s + head] + ad) - m);
            }
        }
        float ws = w;
#pragma unroll
        for (int o = 32; o > 0; o >>= 1) ws += __shfl_xor(ws, o);
        sum += ws;
        int cnt = min(64, end - chunk);
        int j = 0;
        for (; j + 4 <= cnt; j += 4) {
            int   sj0 = __builtin_amdgcn_readlane(s, j);
            int   sj1 = __builtin_amdgcn_readlane(s, j + 1);
            int   sj2 = __builtin_amdgcn_readlane(s, j + 2);
            int   sj3 = __builtin_amdgcn_readlane(s, j + 3);
            float wj0 = readlane_f(w, j);
            float wj1 = readlane_f(w, j + 1);
            float wj2 = readlane_f(w, j + 2);
            float wj3 = readlane_f(w, j + 3);
            float v0 = hh[(size_t)sj0 * 128 + lane];
            float v1 = hh[(size_t)sj1 * 128 + lane];
            float v2 = hh[(size_t)sj2 * 128 + lane];
            float v3 = hh[(size_t)sj3 * 128 + lane];
            acc = fmaf(wj0, v0, acc);
            acc = fmaf(wj1, v1, acc);
            acc = fmaf(wj2, v2, acc);
            acc = fmaf(wj3, v3, acc);
        }
        for (; j < cnt; ++j) {
            int   sj = __builtin_amdgcn_readlane(s, j);
            float wj = readlane_f(w, j);
            acc = fmaf(wj, hh[(size_t)sj * 128 + lane], acc);
        }
    }
    float o0 = acc / (sum + 1e-16f) + bias[head * 64 + lane];
    out[(size_t)node * 128 + head * 64 + lane] = fmaxf(o0, 0.f);
}

// layer2: one wave per node, 1 head, stride 64, no relu
__global__ void agg_layer2(const float* __restrict__ h2, const float* __restrict__ asrc,
                           const float* __restrict__ adst, const int* __restrict__ offs,
                           const int* __restrict__ csr, const float* __restrict__ bias,
                           float* __restrict__ out, int N) {
    int wid = (blockIdx.x * blockDim.x + threadIdx.x) >> 6;
    int lane = threadIdx.x & 63;
    if (wid >= N) return;
    int off = offs[wid], end = offs[wid + 1];
    float ad = adst[wid];
    float self = LEAKY(asrc[wid] + ad);

    int e0 = off + lane;
    int s_reg = 0;
    float alpha_reg = -1e30f;
    if (e0 < end) {
        s_reg = csr[e0];
        alpha_reg = LEAKY(asrc[s_reg] + ad);
    }
    float m = fmaxf(self, alpha_reg);
    for (int e = off + 64 + lane; e < end; e += 64) {
        m = fmaxf(m, LEAKY(asrc[csr[e]] + ad));
    }
#pragma unroll
    for (int o = 32; o > 0; o >>= 1) m = fmaxf(m, __shfl_xor(m, o));

    float wself = __expf(self - m);
    float sum = wself;
    float acc = wself * h2[(size_t)wid * 64 + lane];

    for (int chunk = off; chunk < end; chunk += 64) {
        float w;
        int s;
        if (chunk == off) {
            s = s_reg;
            w = (e0 < end) ? __expf(alpha_reg - m) : 0.f;
        } else {
            int e = chunk + lane;
            s = 0;
            w = 0.f;
            if (e < end) {
                s = csr[e];
                w = __expf(LEAKY(asrc[s] + ad) - m);
            }
        }
        float ws = w;
#pragma unroll
        for (int o = 32; o > 0; o >>= 1) ws += __shfl_xor(ws, o);
        sum += ws;
        int cnt = min(64, end - chunk);
        int j = 0;
        for (; j + 4 <= cnt; j += 4) {
            int   sj0 = __builtin_amdgcn_readlane(s, j);
            int   sj1 = __builtin_amdgcn_readlane(s, j + 1);
            int   sj2 = __builtin_amdgcn_readlane(s, j + 2);
            int   sj3 = __builtin_amdgcn_readlane(s, j + 3);
            float wj0 = readlane_f(w, j);
            float wj1 = readlane_f(w, j + 1);
            float wj2 = readlane_f(w, j + 2);
            float wj3 = readlane_f(w, j + 3);
            float v0 = h2[(size_t)sj0 * 64 + lane];
            float v1 = h2[(size_t)sj1 * 64 + lane];
            float v2 = h2[(size_t)sj2 * 64 + lane];
            float v3 = h2[(size_t)sj3 * 64 + lane];
            acc = fmaf(wj0, v0, acc);
            acc = fmaf(wj1, v1, acc);
            acc = fmaf(wj2, v2, acc);
            acc = fmaf(wj3, v3, acc);
        }
        for (; j < cnt; ++j) {
            int   sj = __builtin_amdgcn_readlane(s, j);
            float wj = readlane_f(w, j);
            acc = fmaf(wj, h2[(size_t)sj * 64 + lane], acc);
        }
    }
    out[(size_t)wid * 64 + lane] = acc / (sum + 1e-16f) + bias[lane];
}

// ---------------------------------------------------------------- host
extern "C" void kernel_launch(void* const* d_in, const int* in_sizes, int n_in,
                              void* d_out, int out_size, void* d_ws, size_t ws_size,
                              hipStream_t stream) {
    const float* x        = (const float*)d_in[0];
    const int* ei         = (const int*)d_in[1];
    const float* W1       = (const float*)d_in[2];
    const float* att_src1 = (const float*)d_in[3];
    const float* att_dst1 = (const float*)d_in[4];
    const float* bias1    = (const float*)d_in[5];
    const float* W2       = (const float*)d_in[6];
    const float* att_src2 = (const float*)d_in[7];
    const float* att_dst2 = (const float*)d_in[8];
    const float* bias2    = (const float*)d_in[9];

    const int N = in_sizes[0] / 128;  // 100000
    const int E = in_sizes[1] / 2;    // 1600000

    char* base = (char*)d_ws;
    size_t off = 0;
    auto alloc = [&](size_t bytes) {
        char* p = base + off;
        off = (off + bytes + 255) & ~(size_t)255;
        return p;
    };
    int*   deg     = (int*)alloc((size_t)N * 4);
    int*   offsets = (int*)alloc((size_t)(N + 1) * 4);
    int*   cursor  = (int*)alloc((size_t)N * 4);
    int*   bsum    = (int*)alloc(4096);
    int*   csr     = (int*)alloc((size_t)E * 4);
    float* h1      = (float*)alloc((size_t)N * 128 * 4);
    float* out1    = (float*)alloc((size_t)N * 128 * 4);
    float* asrc1   = (float*)alloc((size_t)N * 2 * 4);
    float* adst1   = (float*)alloc((size_t)N * 2 * 4);
    float* asrc2   = (float*)alloc((size_t)N * 4);
    float* adst2   = (float*)alloc((size_t)N * 4);
    float* h2      = h1;

    const int nb = (N + 2047) / 2048;

    hipMemsetAsync(deg, 0, (size_t)N * 4, stream);
    hist_dst<<<(E + 255) / 256, 256, 0, stream>>>(ei, E, deg);
    scan_phase1<<<nb, 256, 0, stream>>>(deg, N, bsum);
    scan_phase2<<<1, 64, 0, stream>>>(bsum, nb, offsets, N);
    scan_phase3<<<nb, 256, 0, stream>>>(deg, N, bsum, offsets);
    hipMemcpyAsync(cursor, offsets, (size_t)N * 4, hipMemcpyDeviceToDevice, stream);
    scatter_csr<<<(E + 255) / 256, 256, 0, stream>>>(ei, E, cursor, csr);

    const int mblocks = (N + 63) / 64;
    const int nwave_blocks = (N + 3) / 4;
    const int nwave_blocks2 = (2 * N + 3) / 4;

    // --- layer 1 ---
    gemm_k128<<<dim3(mblocks, 2), dim3(16, 16), 0, stream>>>(x, W1, h1, N, 128);
    att_scores_h2<<<nwave_blocks, 256, 0, stream>>>(h1, att_src1, att_dst1, asrc1, adst1, N);
    agg_layer1<<<nwave_blocks2, 256, 0, stream>>>(h1, asrc1, adst1, offsets, csr, bias1, out1, N);

    // --- layer 2 ---
    gemm_k128<<<dim3(mblocks, 1), dim3(16, 16), 0, stream>>>(out1, W2, h2, N, 64);
    att_scores_h1<<<nwave_blocks, 256, 0, stream>>>(h2, att_src2, att_dst2, asrc2, adst2, N);
    agg_layer2<<<nwave_blocks, 256, 0, stream>>>(h2, asrc2, adst2, offsets, csr, bias2,
                                                 (float*)d_out, N);
}